// Round 3
// baseline (186.641 us; speedup 1.0000x reference)
//
#include <hip/hip_runtime.h>
#include <math.h>

#define SIGMA_BOOST 2.0f
#define EPSILON 1e-6f

// ---------------------------------------------------------------------------
// Per-t parameters {mean_row, mean_col, sigma, pvalue}. Numerics FROZEN from
// the passing round-1 kernel (absmax 9.31 vs threshold 10.48 — index flips at
// round-half boundaries are the error source; do not perturb).
// ---------------------------------------------------------------------------
__device__ __forceinline__ float4 compute_param(const float2* __restrict__ pmeans,
                                                const float* __restrict__ psigmas,
                                                const float* __restrict__ pvalues,
                                                int t, int N) {
    float2 pm = pmeans[t];
    float scale = (float)(N - 1);
    float m0 = __fmul_rn(__fdiv_rn(1.0f, __fadd_rn(1.0f, expf(-pm.x))), scale);
    float m1 = __fmul_rn(__fdiv_rn(1.0f, __fadd_rn(1.0f, expf(-pm.y))), scale);
    float z  = __fadd_rn(psigmas[t], SIGMA_BOOST);
    float sp = __fadd_rn(fmaxf(z, 0.0f), log1pf(expf(-fabsf(z))));
    float sg = __fmul_rn(__fadd_rn(sp, EPSILON), (float)N);
    return make_float4(m0, m1, sg, pvalues[t]);
}

__global__ void params_kernel(const float2* __restrict__ pmeans,
                              const float* __restrict__ psigmas,
                              const float* __restrict__ pvalues,
                              float4* __restrict__ params, int N) {
    int t = blockIdx.x * blockDim.x + threadIdx.x;
    if (t < N) params[t] = compute_param(pmeans, psigmas, pvalues, t, N);
}

// ---------------------------------------------------------------------------
// FAST PATH (N == 2048*U4, block=1024): one block per batch row.
// LDS = [y-acc N floats][x-row N floats] = 128 KB.
// Straight-line per thread: issue ALL 3*U4 global loads (noise + param pairs)
// first -> max memory-level parallelism; stage x/zero y under that latency;
// then indices -> 2*U4 independent ds_reads -> 2*U4 ds atomics.
// j = tid + u*1024 indexes noise float4s; t = 2j, 2j+1.
// __launch_bounds__(1024,4): cap VGPR at 128 so all 16 waves stay resident.
// ---------------------------------------------------------------------------
template <int U4>
__launch_bounds__(1024, 4)
__global__ void contract_fast(const float* __restrict__ x,
                              const float4* __restrict__ noise4,
                              const float4* __restrict__ params,
                              float* __restrict__ y, int N) {
    extern __shared__ float lds[];
    float* ly = lds;
    float* lx = lds + N;
    const int b = blockIdx.x;
    const int tid = threadIdx.x;
    const int nthr = 1024;
    const int n4 = N >> 2;

    const float4* nb4 = noise4 + (size_t)b * (size_t)(N >> 1);

    // --- issue ALL long-latency loads up front (24 independent vmem ops) ---
    float4 nv[U4], pa[U4], pb[U4];
#pragma unroll
    for (int u = 0; u < U4; ++u) {
        int j = tid + u * nthr;
        nv[u] = nb4[j];
        pa[u] = params[2 * j];
        pb[u] = params[2 * j + 1];
    }

    // --- stage x row + zero y accumulator (rides under the load latency) ---
    const float4* xb4 = (const float4*)(x + (size_t)b * N);
    float4* lx4 = (float4*)lx;
    float4* ly4 = (float4*)ly;
#pragma unroll
    for (int i = tid; i < n4; i += nthr) {
        lx4[i] = xb4[i];
        ly4[i] = make_float4(0.f, 0.f, 0.f, 0.f);
    }
    __syncthreads();

    // --- indices: sample = mean + sigma*noise, UNFUSED mul+add (frozen);
    //     rintf = half-to-even = np.round; clamp in float ---
    const float fN1 = (float)(N - 1);
    int r[2 * U4], c[2 * U4];
    float pv[2 * U4];
#pragma unroll
    for (int u = 0; u < U4; ++u) {
        float s0 = __fadd_rn(pa[u].x, __fmul_rn(pa[u].z, nv[u].x));
        float s1 = __fadd_rn(pa[u].y, __fmul_rn(pa[u].z, nv[u].y));
        r[2 * u] = (int)fminf(fmaxf(rintf(s0), 0.f), fN1);
        c[2 * u] = (int)fminf(fmaxf(rintf(s1), 0.f), fN1);
        pv[2 * u] = pa[u].w;
        float s2 = __fadd_rn(pb[u].x, __fmul_rn(pb[u].z, nv[u].z));
        float s3 = __fadd_rn(pb[u].y, __fmul_rn(pb[u].z, nv[u].w));
        r[2 * u + 1] = (int)fminf(fmaxf(rintf(s2), 0.f), fN1);
        c[2 * u + 1] = (int)fminf(fmaxf(rintf(s3), 0.f), fN1);
        pv[2 * u + 1] = pb[u].w;
    }
    // --- 16 independent LDS gathers, then 16 LDS scatter-adds ---
    float xv[2 * U4];
#pragma unroll
    for (int k = 0; k < 2 * U4; ++k) xv[k] = lx[c[k]];
#pragma unroll
    for (int k = 0; k < 2 * U4; ++k) atomicAdd(&ly[r[k]], __fmul_rn(pv[k], xv[k]));
    __syncthreads();

    // --- coalesced write-out ---
    float4* yb4 = (float4*)(y + (size_t)b * N);
#pragma unroll
    for (int i = tid; i < n4; i += nthr) yb4[i] = ly4[i];
}

// ---------------------------------------------------------------------------
// Generic fallback (round-2 structure) for any N / no-ws / small-LDS cases.
// ---------------------------------------------------------------------------
template <bool STAGED, bool INLINE_PARAMS, int UNROLL>
__launch_bounds__(1024, 1)
__global__ void contract_kernel(const float* __restrict__ x,
                                const float2* __restrict__ noise,
                                const float4* __restrict__ params,
                                const float2* __restrict__ pmeans,
                                const float* __restrict__ psigmas,
                                const float* __restrict__ pvalues,
                                float* __restrict__ y, int N) {
    extern __shared__ float lds[];
    float* ly = lds;
    float* lx = STAGED ? (lds + N) : nullptr;

    const int b = blockIdx.x;
    const int tid = threadIdx.x;
    const int nthr = blockDim.x;
    const int n4 = N >> 2;

    const float* xb = x + (size_t)b * N;
    float4* ly4 = (float4*)ly;
    const float4* xb4 = (const float4*)xb;

    if (STAGED) {
        float4* lx4 = (float4*)lx;
        for (int i = tid; i < n4; i += nthr) {
            ly4[i] = make_float4(0.f, 0.f, 0.f, 0.f);
            lx4[i] = xb4[i];
        }
    } else {
        for (int i = tid; i < n4; i += nthr)
            ly4[i] = make_float4(0.f, 0.f, 0.f, 0.f);
    }
    __syncthreads();

    const float4* nb4 = (const float4*)(noise + (size_t)b * N);
    const float fN1 = (float)(N - 1);

    for (int t0 = tid * UNROLL; t0 < N; t0 += nthr * UNROLL) {
        float nz[2 * UNROLL];
#pragma unroll
        for (int u = 0; u < UNROLL / 2; ++u) {
            float4 nvv = nb4[(t0 >> 1) + u];
            nz[4 * u + 0] = nvv.x; nz[4 * u + 1] = nvv.y;
            nz[4 * u + 2] = nvv.z; nz[4 * u + 3] = nvv.w;
        }
        float4 p[UNROLL];
#pragma unroll
        for (int u = 0; u < UNROLL; ++u)
            p[u] = INLINE_PARAMS ? compute_param(pmeans, psigmas, pvalues, t0 + u, N)
                                 : params[t0 + u];
        int r[UNROLL], c[UNROLL];
#pragma unroll
        for (int u = 0; u < UNROLL; ++u) {
            float s0 = __fadd_rn(p[u].x, __fmul_rn(p[u].z, nz[2 * u + 0]));
            float s1 = __fadd_rn(p[u].y, __fmul_rn(p[u].z, nz[2 * u + 1]));
            r[u] = (int)fminf(fmaxf(rintf(s0), 0.0f), fN1);
            c[u] = (int)fminf(fmaxf(rintf(s1), 0.0f), fN1);
        }
        float xvv[UNROLL];
#pragma unroll
        for (int u = 0; u < UNROLL; ++u)
            xvv[u] = STAGED ? lx[c[u]] : xb[c[u]];
#pragma unroll
        for (int u = 0; u < UNROLL; ++u)
            atomicAdd(&ly[r[u]], __fmul_rn(p[u].w, xvv[u]));
    }
    __syncthreads();

    float4* yb4 = (float4*)(y + (size_t)b * N);
    for (int i = tid; i < n4; i += nthr) yb4[i] = ly4[i];
}

extern "C" void kernel_launch(void* const* d_in, const int* in_sizes, int n_in,
                              void* d_out, int out_size, void* d_ws, size_t ws_size,
                              hipStream_t stream) {
    const float*  x       = (const float*)d_in[0];
    const float2* noise   = (const float2*)d_in[1];
    const float2* pmeans  = (const float2*)d_in[2];
    const float*  psigmas = (const float*)d_in[3];
    const float*  pvalues = (const float*)d_in[4];
    float* y = (float*)d_out;

    const int N = in_sizes[3];          // psigmas is (N,)
    const int B = in_sizes[0] / N;      // x is (B,N)

    const size_t params_bytes = (size_t)N * sizeof(float4);
    const bool use_ws = (ws_size >= params_bytes) && (d_ws != nullptr);

    const int block = 1024;
    const size_t staged_lds = 2 * (size_t)N * sizeof(float);  // 128 KB
    const size_t acc_lds    = (size_t)N * sizeof(float);      // 64 KB

    int dev = 0;
    (void)hipGetDevice(&dev);
    int max_lds = 0;
    (void)hipDeviceGetAttribute(&max_lds, hipDeviceAttributeMaxSharedMemoryPerBlock, dev);
    const bool staged = (size_t)max_lds >= staged_lds;

    float4* params = (float4*)d_ws;
    if (use_ws)
        params_kernel<<<(N + 255) / 256, 256, 0, stream>>>(pmeans, psigmas, pvalues, params, N);

    constexpr int U4 = 8;  // N == 2*1024*U4 == 16384
    if (staged && use_ws && N == 2 * 1024 * U4) {
        (void)hipFuncSetAttribute(
            reinterpret_cast<const void*>(&contract_fast<U4>),
            hipFuncAttributeMaxDynamicSharedMemorySize, (int)staged_lds);
        contract_fast<U4><<<B, block, staged_lds, stream>>>(
            x, (const float4*)noise, params, y, N);
    } else if (staged) {
        if (use_ws) {
            (void)hipFuncSetAttribute(
                reinterpret_cast<const void*>(&contract_kernel<true, false, 4>),
                hipFuncAttributeMaxDynamicSharedMemorySize, (int)staged_lds);
            contract_kernel<true, false, 4><<<B, block, staged_lds, stream>>>(
                x, noise, params, nullptr, nullptr, nullptr, y, N);
        } else {
            (void)hipFuncSetAttribute(
                reinterpret_cast<const void*>(&contract_kernel<true, true, 4>),
                hipFuncAttributeMaxDynamicSharedMemorySize, (int)staged_lds);
            contract_kernel<true, true, 4><<<B, block, staged_lds, stream>>>(
                x, noise, nullptr, pmeans, psigmas, pvalues, y, N);
        }
    } else {
        if (use_ws) {
            contract_kernel<false, false, 8><<<B, block, acc_lds, stream>>>(
                x, noise, params, nullptr, nullptr, nullptr, y, N);
        } else {
            contract_kernel<false, true, 8><<<B, block, acc_lds, stream>>>(
                x, noise, nullptr, pmeans, psigmas, pvalues, y, N);
        }
    }
}